// Round 1
// baseline (1167.982 us; speedup 1.0000x reference)
//
#include <hip/hip_runtime.h>

// Depthwise "true" 2D convolution: 3072 independent 128x128 fp32 images,
// each with its own 15x15 fp32 kernel, same-padding 7.
// y[i,j] = sum_{a,b} x[i+7-a, j+7-b] * k[a,b]   (zero outside [0,128))
//
// Layout: 2 blocks per image (64 output rows each). Input strip staged in LDS
// with zero-filled halo (78 rows x 144 cols, 8-col pad each side for aligned
// float4 reads). 256 threads/block, each computes a 4x8 output tile with
// fully unrolled 15x8 FMA inner loops per kernel row.

namespace {

constexpr int P      = 128;           // patch size
constexpr int K      = 15;            // kernel size
constexpr int HALF   = 64;            // output rows per block
constexpr int LROWS  = HALF + K - 1;  // 78 staged rows
constexpr int LW     = 144;           // LDS row width in floats (8 | 128 | 8)
constexpr int NT     = 256;

__global__ __launch_bounds__(NT, 3)
void dwconv_kernel(const float* __restrict__ patches,
                   const float* __restrict__ kernels,
                   float* __restrict__ out)
{
    __shared__ float xs[LROWS * LW];   // 44928 B
    __shared__ float ks[K * 16];       // kernel rows padded to 16 floats

    const int tid   = threadIdx.x;
    const int n     = blockIdx.x >> 1;        // image index 0..3071
    const int halfb = blockIdx.x & 1;
    const int ibase = halfb * HALF;           // first output row of this block

    const float* img  = patches + (size_t)n * (P * P);
    const float* kern = kernels + (size_t)n * (K * K);

    // ---- stage kernel: 15 rows padded to 16 floats, col 15 zeroed ----
    if (tid < K * 16) {
        const int a = tid >> 4;
        const int b = tid & 15;
        ks[tid] = (b < K) ? kern[a * K + b] : 0.0f;
    }

    // ---- stage input strip rows [ibase-7, ibase+70] with zero halo ----
    // 78 rows * 36 float4 = 2808 float4 chunks
    for (int idx = tid; idx < LROWS * (LW / 4); idx += NT) {
        const int row = idx / (LW / 4);
        const int c4  = idx - row * (LW / 4);
        const int r   = ibase - 7 + row;       // global input row
        const int g0  = c4 * 4 - 8;            // global col of first float
        float4 v = make_float4(0.f, 0.f, 0.f, 0.f);
        if ((unsigned)r < (unsigned)P) {
            if (g0 >= 0 && g0 + 3 < P) {
                v = *reinterpret_cast<const float4*>(img + r * P + g0);
            } else {
                float t0 = 0.f, t1 = 0.f, t2 = 0.f, t3 = 0.f;
                const float* rp = img + r * P;
                if ((unsigned)(g0 + 0) < (unsigned)P) t0 = rp[g0 + 0];
                if ((unsigned)(g0 + 1) < (unsigned)P) t1 = rp[g0 + 1];
                if ((unsigned)(g0 + 2) < (unsigned)P) t2 = rp[g0 + 2];
                if ((unsigned)(g0 + 3) < (unsigned)P) t3 = rp[g0 + 3];
                v = make_float4(t0, t1, t2, t3);
            }
        }
        *reinterpret_cast<float4*>(xs + row * LW + c4 * 4) = v;
    }
    __syncthreads();

    // ---- per-thread 4x8 output tile ----
    const int ty = tid >> 4;       // 0..15
    const int tx = tid & 15;       // 0..15
    const int i0 = ty * 4;         // local output row base (0..60)
    const int j0 = tx * 8;         // output col base (0..120)

    float acc[4][8];
    #pragma unroll
    for (int rr = 0; rr < 4; ++rr)
        #pragma unroll
        for (int s = 0; s < 8; ++s)
            acc[rr][s] = 0.0f;

    #pragma unroll 1
    for (int a = 0; a < K; ++a) {
        // broadcast-load kernel row a (16 floats, last is 0)
        float kv[16];
        #pragma unroll
        for (int q = 0; q < 4; ++q) {
            const float4 kk = *reinterpret_cast<const float4*>(ks + a * 16 + q * 4);
            kv[q * 4 + 0] = kk.x;
            kv[q * 4 + 1] = kk.y;
            kv[q * 4 + 2] = kk.z;
            kv[q * 4 + 3] = kk.w;
        }

        #pragma unroll
        for (int rr = 0; rr < 4; ++rr) {
            // LDS row for input row  i + 7 - a, shifted by the -7 halo:
            const int lrow = i0 + rr + (K - 1) - a;          // 0..77, always valid
            const float* xrow = xs + lrow * LW + j0;          // LDS col j0 (global j0-8)
            float xw[24];
            #pragma unroll
            for (int q = 0; q < 6; ++q) {
                const float4 xv = *reinterpret_cast<const float4*>(xrow + q * 4);
                xw[q * 4 + 0] = xv.x;
                xw[q * 4 + 1] = xv.y;
                xw[q * 4 + 2] = xv.z;
                xw[q * 4 + 3] = xv.w;
            }
            // global col j0+s+7-b  ->  xw[s + 15 - b]
            #pragma unroll
            for (int b = 0; b < K; ++b) {
                #pragma unroll
                for (int s = 0; s < 8; ++s) {
                    acc[rr][s] = fmaf(xw[s + 15 - b], kv[b], acc[rr][s]);
                }
            }
        }
    }

    // ---- write 4x8 tile ----
    float* orow = out + (size_t)n * (P * P) + (size_t)(ibase + i0) * P + j0;
    #pragma unroll
    for (int rr = 0; rr < 4; ++rr) {
        *reinterpret_cast<float4*>(orow + rr * P + 0) =
            make_float4(acc[rr][0], acc[rr][1], acc[rr][2], acc[rr][3]);
        *reinterpret_cast<float4*>(orow + rr * P + 4) =
            make_float4(acc[rr][4], acc[rr][5], acc[rr][6], acc[rr][7]);
    }
}

} // namespace

extern "C" void kernel_launch(void* const* d_in, const int* in_sizes, int n_in,
                              void* d_out, int out_size, void* d_ws, size_t ws_size,
                              hipStream_t stream) {
    const float* patches = (const float*)d_in[0];
    const float* kernels = (const float*)d_in[1];
    float* out = (float*)d_out;

    const int n_images = in_sizes[0] / (P * P);   // 3072
    const int grid = n_images * 2;                // 2 blocks per image

    dwconv_kernel<<<grid, NT, 0, stream>>>(patches, kernels, out);
}

// Round 2
// 638.308 us; speedup vs baseline: 1.8298x; 1.8298x over previous
//
#include <hip/hip_runtime.h>

// Depthwise "true" 2D convolution: 3072 independent 128x128 fp32 images,
// each with its own 15x15 fp32 kernel, same-padding 7.
// y[i,j] = sum_{a,b} x[i+7-a, j+7-b] * k[a,b]   (zero outside [0,128))
//
// R1 -> R2 change: XOR bank-swizzled LDS layout. Lane read stride is 8 floats
// (32B), which without swizzle hits only 16/32 banks (2x serialization,
// SQ_LDS_BANK_CONFLICT=4.5e8 at R1). Swizzling float4 slot m to m^((row>>2)&7)
// spreads the 4 ty-groups across all 32 banks: exactly 8 accesses/bank per
// wave b128 = conflict-free minimum.

namespace {

constexpr int P      = 128;           // patch size
constexpr int K      = 15;            // kernel size
constexpr int HALF   = 64;            // output rows per block
constexpr int LROWS  = HALF + K - 1;  // 78 staged rows
constexpr int LM     = 36;            // logical float4 slots per row (144 floats)
constexpr int LWP    = 160;           // physical row width in floats (40 slots; XOR image of [0,36) under ^7 fits in [0,40))
constexpr int NT     = 256;

__device__ __forceinline__ int swz(int row, int m) {
    // physical float4-slot index for logical slot m of row
    return m ^ ((row >> 2) & 7);
}

__global__ __launch_bounds__(NT, 3)
void dwconv_kernel(const float* __restrict__ patches,
                   const float* __restrict__ kernels,
                   float* __restrict__ out)
{
    __shared__ float xs[LROWS * LWP];  // 49920 B, bank-swizzled
    __shared__ float ks[K * 16];       // kernel rows padded to 16 floats

    const int tid   = threadIdx.x;
    const int n     = blockIdx.x >> 1;        // image index 0..3071
    const int halfb = blockIdx.x & 1;
    const int ibase = halfb * HALF;           // first output row of this block

    const float* img  = patches + (size_t)n * (P * P);
    const float* kern = kernels + (size_t)n * (K * K);

    // ---- stage kernel: 15 rows padded to 16 floats, col 15 zeroed ----
    if (tid < K * 16) {
        const int a = tid >> 4;
        const int b = tid & 15;
        ks[tid] = (b < K) ? kern[a * K + b] : 0.0f;
    }

    // ---- stage input strip rows [ibase-7, ibase+70] with zero halo ----
    // 78 rows * 36 float4 chunks; logical col of chunk m is 4m-8 (8-col halo)
    for (int idx = tid; idx < LROWS * LM; idx += NT) {
        const int row = idx / LM;
        const int m   = idx - row * LM;
        const int r   = ibase - 7 + row;       // global input row
        const int g0  = m * 4 - 8;             // global col of first float
        float4 v = make_float4(0.f, 0.f, 0.f, 0.f);
        if ((unsigned)r < (unsigned)P) {
            if (g0 >= 0 && g0 + 3 < P) {
                v = *reinterpret_cast<const float4*>(img + r * P + g0);
            } else {
                float t0 = 0.f, t1 = 0.f, t2 = 0.f, t3 = 0.f;
                const float* rp = img + r * P;
                if ((unsigned)(g0 + 0) < (unsigned)P) t0 = rp[g0 + 0];
                if ((unsigned)(g0 + 1) < (unsigned)P) t1 = rp[g0 + 1];
                if ((unsigned)(g0 + 2) < (unsigned)P) t2 = rp[g0 + 2];
                if ((unsigned)(g0 + 3) < (unsigned)P) t3 = rp[g0 + 3];
                v = make_float4(t0, t1, t2, t3);
            }
        }
        *reinterpret_cast<float4*>(xs + row * LWP + 4 * swz(row, m)) = v;
    }
    __syncthreads();

    // ---- per-thread 4x8 output tile ----
    const int ty = tid >> 4;       // 0..15
    const int tx = tid & 15;       // 0..15
    const int i0 = ty * 4;         // local output row base (0..60)
    const int j0 = tx * 8;         // output col base (0..120)
    const int m0 = tx * 2;         // base logical float4 slot of this thread's window

    float acc[4][8];
    #pragma unroll
    for (int rr = 0; rr < 4; ++rr)
        #pragma unroll
        for (int s = 0; s < 8; ++s)
            acc[rr][s] = 0.0f;

    #pragma unroll 1
    for (int a = 0; a < K; ++a) {
        // broadcast-load kernel row a (16 floats, last is 0)
        float kv[16];
        #pragma unroll
        for (int q = 0; q < 4; ++q) {
            const float4 kk = *reinterpret_cast<const float4*>(ks + a * 16 + q * 4);
            kv[q * 4 + 0] = kk.x;
            kv[q * 4 + 1] = kk.y;
            kv[q * 4 + 2] = kk.z;
            kv[q * 4 + 3] = kk.w;
        }

        #pragma unroll
        for (int rr = 0; rr < 4; ++rr) {
            // LDS row for input row  i + 7 - a, shifted by the -7 halo:
            const int lrow = i0 + rr + (K - 1) - a;          // 0..77, always valid
            const float* xrow = xs + lrow * LWP;
            const int    sw   = (lrow >> 2) & 7;
            float xw[24];
            #pragma unroll
            for (int q = 0; q < 6; ++q) {
                const float4 xv =
                    *reinterpret_cast<const float4*>(xrow + 4 * ((m0 + q) ^ sw));
                xw[q * 4 + 0] = xv.x;
                xw[q * 4 + 1] = xv.y;
                xw[q * 4 + 2] = xv.z;
                xw[q * 4 + 3] = xv.w;
            }
            // global col j0+s+7-b  ->  xw[s + 15 - b]
            #pragma unroll
            for (int b = 0; b < K; ++b) {
                #pragma unroll
                for (int s = 0; s < 8; ++s) {
                    acc[rr][s] = fmaf(xw[s + 15 - b], kv[b], acc[rr][s]);
                }
            }
        }
    }

    // ---- write 4x8 tile ----
    float* orow = out + (size_t)n * (P * P) + (size_t)(ibase + i0) * P + j0;
    #pragma unroll
    for (int rr = 0; rr < 4; ++rr) {
        *reinterpret_cast<float4*>(orow + rr * P + 0) =
            make_float4(acc[rr][0], acc[rr][1], acc[rr][2], acc[rr][3]);
        *reinterpret_cast<float4*>(orow + rr * P + 4) =
            make_float4(acc[rr][4], acc[rr][5], acc[rr][6], acc[rr][7]);
    }
}

} // namespace

extern "C" void kernel_launch(void* const* d_in, const int* in_sizes, int n_in,
                              void* d_out, int out_size, void* d_ws, size_t ws_size,
                              hipStream_t stream) {
    const float* patches = (const float*)d_in[0];
    const float* kernels = (const float*)d_in[1];
    float* out = (float*)d_out;

    const int n_images = in_sizes[0] / (P * P);   // 3072
    const int grid = n_images * 2;                // 2 blocks per image

    dwconv_kernel<<<grid, NT, 0, stream>>>(patches, kernels, out);
}